// Round 10
// baseline (1896.150 us; speedup 1.0000x reference)
//
#include <hip/hip_runtime.h>
#include <hip/hip_bf16.h>
#include <math.h>

static constexpr int NL=4, DM=128, DI=256, DS=16, DTR=8, NC=256;
static constexpr int Bb=24, Lx=3072, T=1024;
static constexpr int ROWS = Bb*T;       // 24576
static constexpr int NCH=8, TC=128;     // scan chunking

typedef __attribute__((ext_vector_type(4))) float f32x4;
typedef __attribute__((ext_vector_type(8))) short bf16x8;

// f32 -> bf16 (round-to-nearest-even), header-independent
static __device__ inline unsigned short f2bf(float f){
  unsigned int u = __float_as_uint(f);
  unsigned int r = (u + 0x7FFFu + ((u >> 16) & 1u)) >> 16;
  return (unsigned short)r;
}

// DPP-based partial-row add: x += x[lane selected by CTRL]; pure VALU, no DS pipe.
template<int CTRL>
static __device__ __forceinline__ float dpp_add(float x){
  int t = __builtin_amdgcn_update_dpp(0, __float_as_int(x), CTRL, 0xF, 0xF, true);
  return x + __int_as_float(t);
}

// ---------------- initial strided conv: x(B,3072) -> h0 (B,1024,128), plus reversed copy
__global__ __launch_bounds__(256) void k_conv0(const float* __restrict__ x,
    const float* __restrict__ cw, const float* __restrict__ cb,
    float* __restrict__ h0f, float* __restrict__ h0b){
  int idx = blockIdx.x*256 + threadIdx.x;     // B*T*DM total
  int c = idx & (DM-1);
  int t = (idx >> 7) & (T-1);
  int b = idx >> 17;
  const float* xr = x + b*Lx;
  float acc = cb[c];
  int base = 3*t - 1;
#pragma unroll
  for (int k=0;k<3;k++){
    int j = base + k;
    float xv = (j>=0 && j<Lx) ? xr[j] : 0.f;
    acc = fmaf(xv, cw[c*3+k], acc);
  }
  h0f[(b*T + t)*DM + c] = acc;
  h0b[(b*T + (T-1-t))*DM + c] = acc;
}

// ---------------- generic f32 -> bf16 cast
__global__ __launch_bounds__(256) void k_cast(const float* __restrict__ src,
    unsigned short* __restrict__ dst, int n){
  int i = blockIdx.x*256 + threadIdx.x;
  if (i < n) dst[i] = f2bf(src[i]);
}

// ---------------- residual add + LayerNorm over DM=128 -> bf16 hn. 1 wave/row, 4 rows/block
__global__ __launch_bounds__(256) void k_add_ln(const float* __restrict__ hin,
    float* __restrict__ res, const float* __restrict__ lnw, const float* __restrict__ lnb,
    unsigned short* __restrict__ hn, int first){
  int row = blockIdx.x*4 + (threadIdx.x >> 6);
  int lane = threadIdx.x & 63;
  const float* hr = hin + (long)row*DM;
  float* rr = res + (long)row*DM;
  float v0 = hr[lane], v1 = hr[lane+64];
  if (!first){ v0 += rr[lane]; v1 += rr[lane+64]; }
  rr[lane] = v0; rr[lane+64] = v1;
  float s = v0+v1;
#pragma unroll
  for (int m=1;m<64;m<<=1) s += __shfl_xor(s, m);
  float mu = s * (1.f/128.f);
  float d0 = v0-mu, d1 = v1-mu;
  float q = d0*d0 + d1*d1;
#pragma unroll
  for (int m=1;m<64;m<<=1) q += __shfl_xor(q, m);
  float rstd = rsqrtf(q*(1.f/128.f) + 1e-5f);
  hn[(long)row*DM+lane]    = f2bf(d0*rstd*lnw[lane]    + lnb[lane]);
  hn[(long)row*DM+lane+64] = f2bf(d1*rstd*lnw[lane+64] + lnb[lane+64]);
}

// ---------------- bf16 MFMA GEMM: C[M][N](f32) = A[M][K](bf16) * W[N][K](bf16)^T
// tile 128x128, 4 waves (2x2), each wave 64x64 via 4x4 frags of 16x16x32
template<int N, int K>
__global__ __launch_bounds__(256) void k_mgemm(const unsigned short* __restrict__ A,
    const unsigned short* __restrict__ W, float* __restrict__ C){
  constexpr int BK = 32;
  __shared__ short As[128*BK];
  __shared__ short Ws[128*BK];
  int tid = threadIdx.x;
  int lane = tid & 63, wave = tid >> 6;
  int wr = (wave >> 1) * 64, wc = (wave & 1) * 64;
  long bm = blockIdx.x, bn = blockIdx.y;
  const short* Ag = (const short*)A + bm*128*K;
  const short* Wg = (const short*)W + bn*128*K;
  f32x4 acc[4][4] = {};
  int r = lane & 15, kg = (lane >> 4) * 8;
  for (int kb = 0; kb < K; kb += BK){
#pragma unroll
    for (int t = 0; t < 2; t++){
      int c = tid + t*256;            // 512 chunks of 16B per 8KB tile
      int row = c >> 2, kc = (c & 3) * 8;
      *(bf16x8*)&As[row*BK + kc] = *(const bf16x8*)&Ag[row*K + kb + kc];
      *(bf16x8*)&Ws[row*BK + kc] = *(const bf16x8*)&Wg[row*K + kb + kc];
    }
    __syncthreads();
    bf16x8 af[4], wf[4];
#pragma unroll
    for (int m=0;m<4;m++) af[m] = *(const bf16x8*)&As[(wr + m*16 + r)*BK + kg];
#pragma unroll
    for (int n=0;n<4;n++) wf[n] = *(const bf16x8*)&Ws[(wc + n*16 + r)*BK + kg];
#pragma unroll
    for (int m=0;m<4;m++)
#pragma unroll
      for (int n=0;n<4;n++)
        acc[m][n] = __builtin_amdgcn_mfma_f32_16x16x32_bf16(af[m], wf[n], acc[m][n], 0, 0, 0);
    __syncthreads();
  }
  float* Cb = C + (bm*128)*N + bn*128;
  int rq = (lane >> 4) * 4, cn = lane & 15;
#pragma unroll
  for (int m=0;m<4;m++)
#pragma unroll
    for (int n=0;n<4;n++)
#pragma unroll
      for (int q=0;q<4;q++)
        Cb[(wr + m*16 + rq + q)*N + wc + n*16 + cn] = acc[m][n][q];
}

// ---------------- BM=64 variant for the N=128 out-GEMM (2x the blocks -> occupancy)
// tile 64x128, 4 waves (2x2), each wave 32x64 via 2x4 frags
template<int N, int K>
__global__ __launch_bounds__(256) void k_mgemm64(const unsigned short* __restrict__ A,
    const unsigned short* __restrict__ W, float* __restrict__ C){
  constexpr int BK = 32;
  __shared__ short As[64*BK];    // 4KB
  __shared__ short Ws[128*BK];   // 8KB
  int tid = threadIdx.x;
  int lane = tid & 63, wave = tid >> 6;
  int wr = (wave >> 1) * 32, wc = (wave & 1) * 64;
  long bm = blockIdx.x, bn = blockIdx.y;
  const short* Ag = (const short*)A + bm*64*K;
  const short* Wg = (const short*)W + bn*128*K;
  f32x4 acc[2][4] = {};
  int r = lane & 15, kg = (lane >> 4) * 8;
  for (int kb = 0; kb < K; kb += BK){
    {
      int c = tid;                       // A: 256 chunks of 16B
      int row = c >> 2, kc = (c & 3) * 8;
      *(bf16x8*)&As[row*BK + kc] = *(const bf16x8*)&Ag[row*K + kb + kc];
#pragma unroll
      for (int t = 0; t < 2; t++){       // W: 512 chunks
        int c2 = tid + t*256;
        int row2 = c2 >> 2, kc2 = (c2 & 3) * 8;
        *(bf16x8*)&Ws[row2*BK + kc2] = *(const bf16x8*)&Wg[row2*K + kb + kc2];
      }
    }
    __syncthreads();
    bf16x8 af[2], wf[4];
#pragma unroll
    for (int m=0;m<2;m++) af[m] = *(const bf16x8*)&As[(wr + m*16 + r)*BK + kg];
#pragma unroll
    for (int n=0;n<4;n++) wf[n] = *(const bf16x8*)&Ws[(wc + n*16 + r)*BK + kg];
#pragma unroll
    for (int m=0;m<2;m++)
#pragma unroll
      for (int n=0;n<4;n++)
        acc[m][n] = __builtin_amdgcn_mfma_f32_16x16x32_bf16(af[m], wf[n], acc[m][n], 0, 0, 0);
    __syncthreads();
  }
  float* Cb = C + (bm*64)*N + bn*128;
  int rq = (lane >> 4) * 4, cn = lane & 15;
#pragma unroll
  for (int m=0;m<2;m++)
#pragma unroll
    for (int n=0;n<4;n++)
#pragma unroll
      for (int q=0;q<4;q++)
        Cb[(wr + m*16 + rq + q)*N + wc + n*16 + cn] = acc[m][n][q];
}

// ---------------- causal depthwise conv (k=4, pad 3 left) + SiLU ; x = xz[...,0:256]
// writes f32 xc (for scans) and bf16 xcb (for dbl MFMA)
__global__ __launch_bounds__(256) void k_convs(const float* __restrict__ xz,
    const float* __restrict__ cw, const float* __restrict__ cb,
    float* __restrict__ xc, unsigned short* __restrict__ xcb){
  int idx = blockIdx.x*256 + threadIdx.x;     // B*T*DI
  int d = idx & (DI-1);
  int t = (idx >> 8) & (T-1);
  int b = idx >> 18;
  const float* xrow = xz + (long)b*T*2*DI;
  float acc = cb[d];
#pragma unroll
  for (int k=0;k<4;k++){
    int tt = t + k - 3;
    float xv = (tt>=0) ? xrow[(long)tt*2*DI + d] : 0.f;
    acc = fmaf(xv, cw[d*4+k], acc);
  }
  float s = acc / (1.f + __expf(-acc));
  long o = (long)(b*T+t)*DI + d;
  xc[o] = s;
  xcb[o] = f2bf(s);
}

// ---------------- dbl = xc @ xp^T (40 cols) via MFMA; dt = softplus(dbl[:,:8]@dtw^T+dtb)
__global__ __launch_bounds__(256) void k_dbldt(const unsigned short* __restrict__ xcb,
    const unsigned short* __restrict__ xpb, const float* __restrict__ dtw,
    const float* __restrict__ dtb, float* __restrict__ gdt, float* __restrict__ bcg){
  constexpr int BP = 264;                    // padded row stride (shorts)
  __shared__ short B_s[48*BP];               // 25344 B
  __shared__ float dbl_s[64][9];             // 2304 B
  __shared__ float bc_s[64][33];             // 8448 B
  int tid = threadIdx.x;
  int lane = tid & 63, wave = tid >> 6;
  int wr = wave * 16;                        // wave's row group
  long row0 = (long)blockIdx.x * 64;
  float w[8];
#pragma unroll
  for (int j=0;j<8;j++) w[j] = dtw[tid*8 + j];
  float bias = dtb[tid];
  for (int c = tid; c < 48*32; c += 256){
    int rowp = c >> 5, k8 = (c & 31) * 8;
    bf16x8 v = {};
    if (rowp < 40) v = *(const bf16x8*)&xpb[rowp*256 + k8];
    *(bf16x8*)&B_s[rowp*BP + k8] = v;
  }
  __syncthreads();
  int cf = lane & 15, hi = lane >> 4;
  const short* Ag = (const short*)xcb + (row0 + wr + cf)*DI + hi*8;
  f32x4 acc[3] = {};
#pragma unroll
  for (int ks = 0; ks < 8; ks++){
    bf16x8 af = *(const bf16x8*)&Ag[ks*32];
#pragma unroll
    for (int n = 0; n < 3; n++){
      bf16x8 bf = *(const bf16x8*)&B_s[(n*16 + cf)*BP + ks*32 + hi*8];
      acc[n] = __builtin_amdgcn_mfma_f32_16x16x32_bf16(af, bf, acc[n], 0, 0, 0);
    }
  }
#pragma unroll
  for (int n = 0; n < 3; n++){
    int col = n*16 + cf;
#pragma unroll
    for (int q = 0; q < 4; q++){
      int row = wr + hi*4 + q;
      float v = acc[n][q];
      if (col < 8)       dbl_s[row][col]    = v;
      else if (col < 40) bc_s[row][col - 8] = v;
    }
  }
  __syncthreads();
#pragma unroll
  for (int i = 0; i < 8; i++){
    int idx = tid + i*256;
    int row = idx >> 5, col = idx & 31;
    bcg[(row0 + row)*32 + col] = bc_s[row][col];
  }
  for (int r = 0; r < 64; r++){
    float a = bias;
#pragma unroll
    for (int j = 0; j < 8; j++) a = fmaf(dbl_s[r][j], w[j], a);
    float sp = (a > 20.f) ? a : log1pf(__expf(a));
    gdt[(row0 + r)*DI + tid] = sp;
  }
}

// ---------------- scan pass 1: per-chunk decay product + local final state (h0=0)
// grid (DI/16, NCH, Bb); block 256 = 16 d x 16 s. NO LDS: direct global loads
// (dt/x are 16-lane broadcasts; b is a 16-float contiguous row -> dedup'd in L1/L2)
__global__ __launch_bounds__(256) void k_scan1(const float* __restrict__ gdt,
    const float* __restrict__ bcg, const float* __restrict__ xc,
    const float* __restrict__ Alog, float* __restrict__ Pd, float* __restrict__ Hl){
  int b = blockIdx.z, ch = blockIdx.y, d0 = blockIdx.x*16;
  int tid = threadIdx.x, s = tid & 15, dl = tid >> 4, d = d0 + dl;
  float A = -__expf(Alog[d*DS + s]);
  long r0 = (long)b*T + ch*TC;
  const float* gdt_p = gdt + r0*DI + d;
  const float* xc_p  = xc  + r0*DI + d;
  const float* b_p   = bcg + r0*32 + s;
  float h = 0.f, lp = 0.f;
  for (int i0 = 0; i0 < TC; i0 += 8){
    float dtv[8], xv[8], bv[8];
#pragma unroll
    for (int j=0;j<8;j++){
      dtv[j] = gdt_p[(i0+j)*DI];
      xv[j]  = xc_p [(i0+j)*DI];
      bv[j]  = b_p  [(i0+j)*32];
    }
#pragma unroll
    for (int j=0;j<8;j++){
      float da = dtv[j]*A;
      lp += da;
      h = fmaf(__expf(da), h, dtv[j]*xv[j]*bv[j]);
    }
  }
  long o = ((long)(b*NCH + ch)*DI + d)*DS + s;
  Pd[o] = __expf(lp);
  Hl[o] = h;
}

// ---------------- scan pass 2: sequential chunk combine -> per-chunk start states
__global__ __launch_bounds__(256) void k_scan2(const float* __restrict__ Pd,
    const float* __restrict__ Hl, float* __restrict__ Hst){
  int idx = blockIdx.x*256 + threadIdx.x;   // b*4096 + (d*16+s)
  int b = idx >> 12, j = idx & 4095;
  long base = (long)b*NCH*4096 + j;
  float h = 0.f;
#pragma unroll
  for (int c=0;c<NCH;c++){
    Hst[base + c*4096] = h;
    h = Pd[base + c*4096]*h + Hl[base + c*4096];
  }
}

// ---------------- scan pass 3: full local scan with correct h0, emit gated y (bf16)
// grid (DI/16, NCH, Bb); block 256 = 16 d x 16 s
// direct global loads (no staging LDS); DPP reduce; y_s only for coalesced pack
__global__ __launch_bounds__(256) void k_scan3(const float* __restrict__ gdt,
    const float* __restrict__ bcg, const float* __restrict__ xc, const float* __restrict__ xz,
    const float* __restrict__ Alog, const float* __restrict__ Dp,
    const float* __restrict__ Hst, unsigned short* __restrict__ yg){
  int b = blockIdx.z, ch = blockIdx.y, d0 = blockIdx.x*16;
  int tid = threadIdx.x, s = tid & 15, dl = tid >> 4, d = d0 + dl;
  float A = -__expf(Alog[d*DS + s]);
  float Dd = Dp[d];
  __shared__ float y_s[TC][16];
  long r0 = (long)b*T + ch*TC;
  const float* gdt_p = gdt + r0*DI + d;
  const float* xc_p  = xc  + r0*DI + d;
  const float* z_p   = xz  + r0*2*DI + DI + d;
  const float* b_p   = bcg + r0*32 + s;
  const float* c_p   = b_p + 16;
  float h = Hst[((long)(b*NCH + ch)*DI + d)*DS + s];
  for (int i0 = 0; i0 < TC; i0 += 8){
    float dtv[8], xv[8], bv[8], cv[8], dec[8], ad[8], p[8];
#pragma unroll
    for (int j=0;j<8;j++){
      dtv[j] = gdt_p[(i0+j)*DI];
      xv[j]  = xc_p [(i0+j)*DI];
      bv[j]  = b_p  [(i0+j)*32];
      cv[j]  = c_p  [(i0+j)*32];
    }
#pragma unroll
    for (int j=0;j<8;j++){ dec[j] = __expf(dtv[j]*A); ad[j] = dtv[j]*xv[j]*bv[j]; }
#pragma unroll
    for (int j=0;j<8;j++){ h = fmaf(dec[j], h, ad[j]); p[j] = h * cv[j]; }
    // 4-stage DPP reduce (toward lane 0), 8 independent chains per stage
#pragma unroll
    for (int j=0;j<8;j++) p[j] = dpp_add<0xB1>(p[j]);
#pragma unroll
    for (int j=0;j<8;j++) p[j] = dpp_add<0x4E>(p[j]);
#pragma unroll
    for (int j=0;j<8;j++) p[j] = dpp_add<0x114>(p[j]);
#pragma unroll
    for (int j=0;j<8;j++) p[j] = dpp_add<0x118>(p[j]);
    if (s == 0){
#pragma unroll
      for (int j=0;j<8;j++){
        float zv = z_p[(i0+j)*2*DI];
        float sz = zv / (1.f + __expf(-zv));
        y_s[i0+j][dl] = fmaf(Dd, xv[j], p[j]) * sz;
      }
    }
  }
  __syncthreads();
  // coalesced bf16 pack + store: 16 bf16 per row = 2 x 16B
  for (int lin = tid; lin < TC*2; lin += 256){
    int i = lin >> 1, dd8 = (lin & 1)*8;
    bf16x8 v;
#pragma unroll
    for (int k=0;k<8;k++) v[k] = (short)f2bf(y_s[i][dd8+k]);
    *(bf16x8*)&yg[(r0+i)*DI + d0 + dd8] = v;
  }
}

// ---------------- final-row LN (only t = T-1 needed) -> comb half
__global__ __launch_bounds__(64) void k_final(const float* __restrict__ hcur,
    const float* __restrict__ res, const float* __restrict__ nfw, const float* __restrict__ nfb,
    float* __restrict__ comb, int half){
  int b = blockIdx.x;
  int lane = threadIdx.x;
  const float* h = hcur + ((long)b*T + (T-1))*DM;
  const float* r = res  + ((long)b*T + (T-1))*DM;
  float v0 = h[lane]+r[lane], v1 = h[lane+64]+r[lane+64];
  float s = v0+v1;
#pragma unroll
  for (int m=1;m<64;m<<=1) s += __shfl_xor(s, m);
  float mu = s * (1.f/128.f);
  float d0 = v0-mu, d1 = v1-mu;
  float q = d0*d0 + d1*d1;
#pragma unroll
  for (int m=1;m<64;m<<=1) q += __shfl_xor(q, m);
  float rstd = rsqrtf(q*(1.f/128.f) + 1e-5f);
  comb[b*2*DM + half*DM + lane]    = d0*rstd*nfw[lane]    + nfb[lane];
  comb[b*2*DM + half*DM + lane+64] = d1*rstd*nfw[lane+64] + nfb[lane+64];
}

// ---------------- head: out(24,256) = comb(24,256) @ head_w^T + head_b
__global__ __launch_bounds__(256) void k_head(const float* __restrict__ comb,
    const float* __restrict__ hw, const float* __restrict__ hb, float* __restrict__ out){
  int b = blockIdx.x, n = threadIdx.x;
  const float* cr = comb + b*2*DM;
  float acc = hb[n];
#pragma unroll 4
  for (int k=0;k<2*DM;k++) acc = fmaf(cr[k], hw[n*2*DM + k], acc);
  out[b*NC + n] = acc;
}

extern "C" void kernel_launch(void* const* d_in, const int* in_sizes, int n_in,
                              void* d_out, int out_size, void* d_ws, size_t ws_size,
                              hipStream_t stream){
  auto F = [&](int i){ return (const float*)d_in[i]; };
  float* ws = (float*)d_ws;
  size_t o = 0;
  float* h0f = ws + o; o += (size_t)ROWS*DM;
  float* h0b = ws + o; o += (size_t)ROWS*DM;
  float* res = ws + o; o += (size_t)ROWS*DM;
  float* hcur= ws + o; o += (size_t)ROWS*DM;
  float* xz  = ws + o; o += (size_t)ROWS*2*DI;
  float* xc  = ws + o; o += (size_t)ROWS*DI;
  float* gdt = ws + o; o += (size_t)ROWS*DI;
  float* bcg = ws + o; o += (size_t)ROWS*2*DS;
  // bf16 region shared by hn (ROWS*DM), xcb (ROWS*DI), y (ROWS*DI):
  // per-layer lifetimes disjoint: hn -> xz-gemm; xcb: convs -> dbldt; y: scan3 -> out-gemm
  unsigned short* ybf = (unsigned short*)(ws + o); o += (size_t)ROWS*DI/2;
  unsigned short* hnbf = ybf;
  unsigned short* xcb  = ybf;
  float* Pd  = ws + o; o += (size_t)Bb*NCH*DI*DS;
  float* Hl  = ws + o; o += (size_t)Bb*NCH*DI*DS;
  float* Hst = ws + o; o += (size_t)Bb*NCH*DI*DS;
  unsigned short* wbf = (unsigned short*)(ws + o); o += (size_t)2*NL*(2*DI*DM + DM*DI)/2;
  unsigned short* xpb = (unsigned short*)(ws + o); o += (size_t)2*NL*40*DI/2;
  float* comb= ws + o; o += (size_t)Bb*2*DM;

  // weight casts: [f_inp][f_outp][b_inp][b_outp] + xp (both dirs)
  const int NI = NL*2*DI*DM;   // 262144
  const int NO = NL*DM*DI;     // 131072
  const int NX = NL*40*DI;     // 40960
  k_cast<<<(NI+255)/256, 256, 0, stream>>>(F(3),  wbf,            NI);
  k_cast<<<(NO+255)/256, 256, 0, stream>>>(F(11), wbf+NI,         NO);
  k_cast<<<(NI+255)/256, 256, 0, stream>>>(F(14), wbf+NI+NO,      NI);
  k_cast<<<(NO+255)/256, 256, 0, stream>>>(F(22), wbf+2*NI+NO,    NO);
  k_cast<<<(NX+255)/256, 256, 0, stream>>>(F(6),  xpb,            NX);
  k_cast<<<(NX+255)/256, 256, 0, stream>>>(F(17), xpb+NX,         NX);

  k_conv0<<<ROWS*DM/256, 256, 0, stream>>>(F(0), F(1), F(2), h0f, h0b);

  for (int dir = 0; dir < 2; dir++){
    int p = dir ? 14 : 3;   // f_* at 3..13, b_* at 14..24
    const float* hin = dir ? h0b : h0f;
    unsigned short* winp  = wbf + (size_t)dir*(NI+NO);
    unsigned short* woutp = winp + NI;
    for (int l = 0; l < NL; l++){
      const float* hsrc = (l==0) ? hin : hcur;
      k_add_ln<<<ROWS/4, 256, 0, stream>>>(hsrc, res,
          F(p+9)+(size_t)l*DM, F(p+10)+(size_t)l*DM, hnbf, (l==0)?1:0);
      k_mgemm<2*DI, DM><<<dim3(ROWS/128, (2*DI)/128), 256, 0, stream>>>(
          hnbf, winp + (size_t)l*2*DI*DM, xz);
      k_convs<<<ROWS*DI/256, 256, 0, stream>>>(xz,
          F(p+1)+(size_t)l*DI*4, F(p+2)+(size_t)l*DI, xc, xcb);
      k_dbldt<<<ROWS/64, 256, 0, stream>>>(xcb,
          xpb + (size_t)(dir*NL + l)*40*DI,
          F(p+4)+(size_t)l*DI*DTR, F(p+5)+(size_t)l*DI, gdt, bcg);
      k_scan1<<<dim3(DI/16, NCH, Bb), 256, 0, stream>>>(gdt, bcg, xc,
          F(p+6)+(size_t)l*DI*DS, Pd, Hl);
      k_scan2<<<(Bb*DI*DS)/256, 256, 0, stream>>>(Pd, Hl, Hst);
      k_scan3<<<dim3(DI/16, NCH, Bb), 256, 0, stream>>>(gdt, bcg, xc, xz,
          F(p+6)+(size_t)l*DI*DS, F(p+7)+(size_t)l*DI, Hst, ybf);
      k_mgemm64<DM, DI><<<dim3(ROWS/64, DM/128), 256, 0, stream>>>(
          ybf, woutp + (size_t)l*DM*DI, hcur);
    }
    k_final<<<Bb, 64, 0, stream>>>(hcur, res, F(25), F(26), comb, dir);
  }
  k_head<<<Bb, 256, 0, stream>>>(comb, F(27), F(28), (float*)d_out);
}

// Round 11
// 1853.691 us; speedup vs baseline: 1.0229x; 1.0229x over previous
//
#include <hip/hip_runtime.h>
#include <hip/hip_bf16.h>
#include <math.h>

static constexpr int NL=4, DM=128, DI=256, DS=16, DTR=8, NC=256;
static constexpr int Bb=24, Lx=3072, T=1024;
static constexpr int ROWS = Bb*T;       // 24576
static constexpr int NCH=8, TC=128;     // scan chunking

typedef __attribute__((ext_vector_type(4))) float f32x4;
typedef __attribute__((ext_vector_type(8))) short bf16x8;

// f32 -> bf16 (round-to-nearest-even), header-independent
static __device__ inline unsigned short f2bf(float f){
  unsigned int u = __float_as_uint(f);
  unsigned int r = (u + 0x7FFFu + ((u >> 16) & 1u)) >> 16;
  return (unsigned short)r;
}

// DPP-based partial-row add: x += x[lane selected by CTRL]; pure VALU, no DS pipe.
template<int CTRL>
static __device__ __forceinline__ float dpp_add(float x){
  int t = __builtin_amdgcn_update_dpp(0, __float_as_int(x), CTRL, 0xF, 0xF, true);
  return x + __int_as_float(t);
}

// ---------------- initial strided conv: x(B,3072) -> h0 (B,1024,128), plus reversed copy
__global__ __launch_bounds__(256) void k_conv0(const float* __restrict__ x,
    const float* __restrict__ cw, const float* __restrict__ cb,
    float* __restrict__ h0f, float* __restrict__ h0b){
  int idx = blockIdx.x*256 + threadIdx.x;     // B*T*DM total
  int c = idx & (DM-1);
  int t = (idx >> 7) & (T-1);
  int b = idx >> 17;
  const float* xr = x + b*Lx;
  float acc = cb[c];
  int base = 3*t - 1;
#pragma unroll
  for (int k=0;k<3;k++){
    int j = base + k;
    float xv = (j>=0 && j<Lx) ? xr[j] : 0.f;
    acc = fmaf(xv, cw[c*3+k], acc);
  }
  h0f[(b*T + t)*DM + c] = acc;
  h0b[(b*T + (T-1-t))*DM + c] = acc;
}

// ---------------- generic f32 -> bf16 cast
__global__ __launch_bounds__(256) void k_cast(const float* __restrict__ src,
    unsigned short* __restrict__ dst, int n){
  int i = blockIdx.x*256 + threadIdx.x;
  if (i < n) dst[i] = f2bf(src[i]);
}

// ---------------- residual add + LayerNorm over DM=128 -> bf16 hn. 1 wave/row, 4 rows/block
__global__ __launch_bounds__(256) void k_add_ln(const float* __restrict__ hin,
    float* __restrict__ res, const float* __restrict__ lnw, const float* __restrict__ lnb,
    unsigned short* __restrict__ hn, int first){
  int row = blockIdx.x*4 + (threadIdx.x >> 6);
  int lane = threadIdx.x & 63;
  const float* hr = hin + (long)row*DM;
  float* rr = res + (long)row*DM;
  float v0 = hr[lane], v1 = hr[lane+64];
  if (!first){ v0 += rr[lane]; v1 += rr[lane+64]; }
  rr[lane] = v0; rr[lane+64] = v1;
  float s = v0+v1;
#pragma unroll
  for (int m=1;m<64;m<<=1) s += __shfl_xor(s, m);
  float mu = s * (1.f/128.f);
  float d0 = v0-mu, d1 = v1-mu;
  float q = d0*d0 + d1*d1;
#pragma unroll
  for (int m=1;m<64;m<<=1) q += __shfl_xor(q, m);
  float rstd = rsqrtf(q*(1.f/128.f) + 1e-5f);
  hn[(long)row*DM+lane]    = f2bf(d0*rstd*lnw[lane]    + lnb[lane]);
  hn[(long)row*DM+lane+64] = f2bf(d1*rstd*lnw[lane+64] + lnb[lane+64]);
}

// ---------------- bf16 MFMA GEMM: C[M][N](f32) = A[M][K](bf16) * W[N][K](bf16)^T
// tile 128x128, 4 waves (2x2), each wave 64x64 via 4x4 frags of 16x16x32
template<int N, int K>
__global__ __launch_bounds__(256) void k_mgemm(const unsigned short* __restrict__ A,
    const unsigned short* __restrict__ W, float* __restrict__ C){
  constexpr int BK = 32;
  __shared__ short As[128*BK];
  __shared__ short Ws[128*BK];
  int tid = threadIdx.x;
  int lane = tid & 63, wave = tid >> 6;
  int wr = (wave >> 1) * 64, wc = (wave & 1) * 64;
  long bm = blockIdx.x, bn = blockIdx.y;
  const short* Ag = (const short*)A + bm*128*K;
  const short* Wg = (const short*)W + bn*128*K;
  f32x4 acc[4][4] = {};
  int r = lane & 15, kg = (lane >> 4) * 8;
  for (int kb = 0; kb < K; kb += BK){
#pragma unroll
    for (int t = 0; t < 2; t++){
      int c = tid + t*256;            // 512 chunks of 16B per 8KB tile
      int row = c >> 2, kc = (c & 3) * 8;
      *(bf16x8*)&As[row*BK + kc] = *(const bf16x8*)&Ag[row*K + kb + kc];
      *(bf16x8*)&Ws[row*BK + kc] = *(const bf16x8*)&Wg[row*K + kb + kc];
    }
    __syncthreads();
    bf16x8 af[4], wf[4];
#pragma unroll
    for (int m=0;m<4;m++) af[m] = *(const bf16x8*)&As[(wr + m*16 + r)*BK + kg];
#pragma unroll
    for (int n=0;n<4;n++) wf[n] = *(const bf16x8*)&Ws[(wc + n*16 + r)*BK + kg];
#pragma unroll
    for (int m=0;m<4;m++)
#pragma unroll
      for (int n=0;n<4;n++)
        acc[m][n] = __builtin_amdgcn_mfma_f32_16x16x32_bf16(af[m], wf[n], acc[m][n], 0, 0, 0);
    __syncthreads();
  }
  float* Cb = C + (bm*128)*N + bn*128;
  int rq = (lane >> 4) * 4, cn = lane & 15;
#pragma unroll
  for (int m=0;m<4;m++)
#pragma unroll
    for (int n=0;n<4;n++)
#pragma unroll
      for (int q=0;q<4;q++)
        Cb[(wr + m*16 + rq + q)*N + wc + n*16 + cn] = acc[m][n][q];
}

// ---------------- BM=64 variant for the N=128 out-GEMM (2x the blocks -> occupancy)
template<int N, int K>
__global__ __launch_bounds__(256) void k_mgemm64(const unsigned short* __restrict__ A,
    const unsigned short* __restrict__ W, float* __restrict__ C){
  constexpr int BK = 32;
  __shared__ short As[64*BK];    // 4KB
  __shared__ short Ws[128*BK];   // 8KB
  int tid = threadIdx.x;
  int lane = tid & 63, wave = tid >> 6;
  int wr = (wave >> 1) * 32, wc = (wave & 1) * 64;
  long bm = blockIdx.x, bn = blockIdx.y;
  const short* Ag = (const short*)A + bm*64*K;
  const short* Wg = (const short*)W + bn*128*K;
  f32x4 acc[2][4] = {};
  int r = lane & 15, kg = (lane >> 4) * 8;
  for (int kb = 0; kb < K; kb += BK){
    {
      int c = tid;                       // A: 256 chunks of 16B
      int row = c >> 2, kc = (c & 3) * 8;
      *(bf16x8*)&As[row*BK + kc] = *(const bf16x8*)&Ag[row*K + kb + kc];
#pragma unroll
      for (int t = 0; t < 2; t++){       // W: 512 chunks
        int c2 = tid + t*256;
        int row2 = c2 >> 2, kc2 = (c2 & 3) * 8;
        *(bf16x8*)&Ws[row2*BK + kc2] = *(const bf16x8*)&Wg[row2*K + kb + kc2];
      }
    }
    __syncthreads();
    bf16x8 af[2], wf[4];
#pragma unroll
    for (int m=0;m<2;m++) af[m] = *(const bf16x8*)&As[(wr + m*16 + r)*BK + kg];
#pragma unroll
    for (int n=0;n<4;n++) wf[n] = *(const bf16x8*)&Ws[(wc + n*16 + r)*BK + kg];
#pragma unroll
    for (int m=0;m<2;m++)
#pragma unroll
      for (int n=0;n<4;n++)
        acc[m][n] = __builtin_amdgcn_mfma_f32_16x16x32_bf16(af[m], wf[n], acc[m][n], 0, 0, 0);
    __syncthreads();
  }
  float* Cb = C + (bm*64)*N + bn*128;
  int rq = (lane >> 4) * 4, cn = lane & 15;
#pragma unroll
  for (int m=0;m<2;m++)
#pragma unroll
    for (int n=0;n<4;n++)
#pragma unroll
      for (int q=0;q<4;q++)
        Cb[(wr + m*16 + rq + q)*N + wc + n*16 + cn] = acc[m][n][q];
}

// ---------------- causal depthwise conv (k=4, pad 3 left) + SiLU ; x = xz[...,0:256]
// writes f32 xc (for scans) and bf16 xcb (for dbl MFMA)
__global__ __launch_bounds__(256) void k_convs(const float* __restrict__ xz,
    const float* __restrict__ cw, const float* __restrict__ cb,
    float* __restrict__ xc, unsigned short* __restrict__ xcb){
  int idx = blockIdx.x*256 + threadIdx.x;     // B*T*DI
  int d = idx & (DI-1);
  int t = (idx >> 8) & (T-1);
  int b = idx >> 18;
  const float* xrow = xz + (long)b*T*2*DI;
  float acc = cb[d];
#pragma unroll
  for (int k=0;k<4;k++){
    int tt = t + k - 3;
    float xv = (tt>=0) ? xrow[(long)tt*2*DI + d] : 0.f;
    acc = fmaf(xv, cw[d*4+k], acc);
  }
  float s = acc / (1.f + __expf(-acc));
  long o = (long)(b*T+t)*DI + d;
  xc[o] = s;
  xcb[o] = f2bf(s);
}

// ---------------- dbl = xc @ xp^T (40 cols) via MFMA; dt = softplus(dbl[:,:8]@dtw^T+dtb)
__global__ __launch_bounds__(256) void k_dbldt(const unsigned short* __restrict__ xcb,
    const unsigned short* __restrict__ xpb, const float* __restrict__ dtw,
    const float* __restrict__ dtb, float* __restrict__ gdt, float* __restrict__ bcg){
  constexpr int BP = 264;                    // padded row stride (shorts)
  __shared__ short B_s[48*BP];               // 25344 B
  __shared__ float dbl_s[64][9];             // 2304 B
  __shared__ float bc_s[64][33];             // 8448 B
  int tid = threadIdx.x;
  int lane = tid & 63, wave = tid >> 6;
  int wr = wave * 16;                        // wave's row group
  long row0 = (long)blockIdx.x * 64;
  float w[8];
#pragma unroll
  for (int j=0;j<8;j++) w[j] = dtw[tid*8 + j];
  float bias = dtb[tid];
  for (int c = tid; c < 48*32; c += 256){
    int rowp = c >> 5, k8 = (c & 31) * 8;
    bf16x8 v = {};
    if (rowp < 40) v = *(const bf16x8*)&xpb[rowp*256 + k8];
    *(bf16x8*)&B_s[rowp*BP + k8] = v;
  }
  __syncthreads();
  int cf = lane & 15, hi = lane >> 4;
  const short* Ag = (const short*)xcb + (row0 + wr + cf)*DI + hi*8;
  f32x4 acc[3] = {};
#pragma unroll
  for (int ks = 0; ks < 8; ks++){
    bf16x8 af = *(const bf16x8*)&Ag[ks*32];
#pragma unroll
    for (int n = 0; n < 3; n++){
      bf16x8 bf = *(const bf16x8*)&B_s[(n*16 + cf)*BP + ks*32 + hi*8];
      acc[n] = __builtin_amdgcn_mfma_f32_16x16x32_bf16(af, bf, acc[n], 0, 0, 0);
    }
  }
#pragma unroll
  for (int n = 0; n < 3; n++){
    int col = n*16 + cf;
#pragma unroll
    for (int q = 0; q < 4; q++){
      int row = wr + hi*4 + q;
      float v = acc[n][q];
      if (col < 8)       dbl_s[row][col]    = v;
      else if (col < 40) bc_s[row][col - 8] = v;
    }
  }
  __syncthreads();
#pragma unroll
  for (int i = 0; i < 8; i++){
    int idx = tid + i*256;
    int row = idx >> 5, col = idx & 31;
    bcg[(row0 + row)*32 + col] = bc_s[row][col];
  }
  for (int r = 0; r < 64; r++){
    float a = bias;
#pragma unroll
    for (int j = 0; j < 8; j++) a = fmaf(dbl_s[r][j], w[j], a);
    float sp = (a > 20.f) ? a : log1pf(__expf(a));
    gdt[(row0 + r)*DI + tid] = sp;
  }
}

// ---------------- scan pass 1: per-chunk decay product + local final state (h0=0)
// grid (DI/16, NCH, Bb); block 256 = 16 d x 16 s
// transposed LDS [col][i], stride 132 -> ds_read_b128, immediate offsets
__global__ __launch_bounds__(256) void k_scan1(const float* __restrict__ gdt,
    const float* __restrict__ bcg, const float* __restrict__ xc,
    const float* __restrict__ Alog, float* __restrict__ Pd, float* __restrict__ Hl){
  constexpr int ST = 132;
  __shared__ float dt_s[16*ST], x_s[16*ST], b_s[16*ST];
  int b = blockIdx.z, ch = blockIdx.y, d0 = blockIdx.x*16;
  int tid = threadIdx.x, s = tid & 15, dl = tid >> 4, d = d0 + dl;
  float A = -__expf(Alog[d*DS + s]);
  long r0 = (long)b*T + ch*TC;
  for (int lin = tid; lin < TC*4; lin += 256){
    int i = lin >> 2, c4 = (lin & 3) * 4;
    float4 dv = *(const float4*)&gdt[(r0+i)*DI + d0 + c4];
    float4 xv = *(const float4*)&xc [(r0+i)*DI + d0 + c4];
    float4 bv = *(const float4*)&bcg[(r0+i)*32 + c4];     // cols 0..15 = B
    dt_s[(c4+0)*ST+i]=dv.x; dt_s[(c4+1)*ST+i]=dv.y; dt_s[(c4+2)*ST+i]=dv.z; dt_s[(c4+3)*ST+i]=dv.w;
    x_s [(c4+0)*ST+i]=xv.x; x_s [(c4+1)*ST+i]=xv.y; x_s [(c4+2)*ST+i]=xv.z; x_s [(c4+3)*ST+i]=xv.w;
    b_s [(c4+0)*ST+i]=bv.x; b_s [(c4+1)*ST+i]=bv.y; b_s [(c4+2)*ST+i]=bv.z; b_s [(c4+3)*ST+i]=bv.w;
  }
  __syncthreads();
  float h = 0.f, lp = 0.f;
  for (int i0 = 0; i0 < TC; i0 += 8){
    float4 da4 = *(const float4*)&dt_s[dl*ST + i0];
    float4 db4 = *(const float4*)&dt_s[dl*ST + i0 + 4];
    float4 xa4 = *(const float4*)&x_s [dl*ST + i0];
    float4 xb4 = *(const float4*)&x_s [dl*ST + i0 + 4];
    float4 ba4 = *(const float4*)&b_s [s*ST + i0];
    float4 bb4 = *(const float4*)&b_s [s*ST + i0 + 4];
    float dtv[8] = {da4.x,da4.y,da4.z,da4.w,db4.x,db4.y,db4.z,db4.w};
    float xv [8] = {xa4.x,xa4.y,xa4.z,xa4.w,xb4.x,xb4.y,xb4.z,xb4.w};
    float bv [8] = {ba4.x,ba4.y,ba4.z,ba4.w,bb4.x,bb4.y,bb4.z,bb4.w};
#pragma unroll
    for (int j=0;j<8;j++){
      float daj = dtv[j]*A;
      lp += daj;
      h = fmaf(__expf(daj), h, dtv[j]*xv[j]*bv[j]);
    }
  }
  long o = ((long)(b*NCH + ch)*DI + d)*DS + s;
  Pd[o] = __expf(lp);
  Hl[o] = h;
}

// ---------------- scan pass 2: sequential chunk combine -> per-chunk start states
__global__ __launch_bounds__(256) void k_scan2(const float* __restrict__ Pd,
    const float* __restrict__ Hl, float* __restrict__ Hst){
  int idx = blockIdx.x*256 + threadIdx.x;   // b*4096 + (d*16+s)
  int b = idx >> 12, j = idx & 4095;
  long base = (long)b*NCH*4096 + j;
  float h = 0.f;
#pragma unroll
  for (int c=0;c<NCH;c++){
    Hst[base + c*4096] = h;
    h = Pd[base + c*4096]*h + Hl[base + c*4096];
  }
}

// ---------------- scan pass 3: full local scan with correct h0, emit gated y (bf16)
// grid (DI/16, NCH, Bb); block 256 = 16 d x 16 s
// transposed LDS (stride 132) -> b128 reads; z read from global by s==0 lanes only;
// DPP reduce; bf16 y buffer for coalesced store. LDS = 37.9 KB -> 4 blocks/CU
__global__ __launch_bounds__(256) void k_scan3(const float* __restrict__ gdt,
    const float* __restrict__ bcg, const float* __restrict__ xc, const float* __restrict__ xz,
    const float* __restrict__ Alog, const float* __restrict__ Dp,
    const float* __restrict__ Hst, unsigned short* __restrict__ yg){
  constexpr int ST = 132;
  __shared__ float dt_s[16*ST], x_s[16*ST], b_s[16*ST], c_s[16*ST];
  __shared__ unsigned short y16[TC*16];
  int b = blockIdx.z, ch = blockIdx.y, d0 = blockIdx.x*16;
  int tid = threadIdx.x, s = tid & 15, dl = tid >> 4, d = d0 + dl;
  float A = -__expf(Alog[d*DS + s]);
  float Dd = Dp[d];
  long r0 = (long)b*T + ch*TC;
  for (int lin = tid; lin < TC*4; lin += 256){
    int i = lin >> 2, c4 = (lin & 3) * 4;
    float4 dv = *(const float4*)&gdt[(r0+i)*DI + d0 + c4];
    float4 xv = *(const float4*)&xc [(r0+i)*DI + d0 + c4];
    dt_s[(c4+0)*ST+i]=dv.x; dt_s[(c4+1)*ST+i]=dv.y; dt_s[(c4+2)*ST+i]=dv.z; dt_s[(c4+3)*ST+i]=dv.w;
    x_s [(c4+0)*ST+i]=xv.x; x_s [(c4+1)*ST+i]=xv.y; x_s [(c4+2)*ST+i]=xv.z; x_s [(c4+3)*ST+i]=xv.w;
  }
  for (int lin = tid; lin < TC*8; lin += 256){
    int i = lin >> 3, c4 = (lin & 7) * 4;   // bcg cols 0..31
    float4 v = *(const float4*)&bcg[(r0+i)*32 + c4];
    float* dst = (c4 < 16) ? &b_s[c4*ST] : &c_s[(c4-16)*ST];
    dst[0*ST+i]=v.x; dst[1*ST+i]=v.y; dst[2*ST+i]=v.z; dst[3*ST+i]=v.w;
  }
  float h = Hst[((long)(b*NCH + ch)*DI + d)*DS + s];
  __syncthreads();
  const float* zb = xz + r0*2*DI + DI + d;
  for (int i0 = 0; i0 < TC; i0 += 8){
    float4 da4 = *(const float4*)&dt_s[dl*ST + i0];
    float4 db4 = *(const float4*)&dt_s[dl*ST + i0 + 4];
    float4 xa4 = *(const float4*)&x_s [dl*ST + i0];
    float4 xb4 = *(const float4*)&x_s [dl*ST + i0 + 4];
    float4 ba4 = *(const float4*)&b_s [s*ST + i0];
    float4 bb4 = *(const float4*)&b_s [s*ST + i0 + 4];
    float4 ca4 = *(const float4*)&c_s [s*ST + i0];
    float4 cb4 = *(const float4*)&c_s [s*ST + i0 + 4];
    float dtv[8] = {da4.x,da4.y,da4.z,da4.w,db4.x,db4.y,db4.z,db4.w};
    float xv [8] = {xa4.x,xa4.y,xa4.z,xa4.w,xb4.x,xb4.y,xb4.z,xb4.w};
    float bv [8] = {ba4.x,ba4.y,ba4.z,ba4.w,bb4.x,bb4.y,bb4.z,bb4.w};
    float cv [8] = {ca4.x,ca4.y,ca4.z,ca4.w,cb4.x,cb4.y,cb4.z,cb4.w};
    float dec[8], ad[8], p[8];
#pragma unroll
    for (int j=0;j<8;j++){ dec[j] = __expf(dtv[j]*A); ad[j] = dtv[j]*xv[j]*bv[j]; }
#pragma unroll
    for (int j=0;j<8;j++){ h = fmaf(dec[j], h, ad[j]); p[j] = h * cv[j]; }
    // 4-stage DPP reduce (toward lane 0), 8 independent chains per stage
#pragma unroll
    for (int j=0;j<8;j++) p[j] = dpp_add<0xB1>(p[j]);
#pragma unroll
    for (int j=0;j<8;j++) p[j] = dpp_add<0x4E>(p[j]);
#pragma unroll
    for (int j=0;j<8;j++) p[j] = dpp_add<0x114>(p[j]);
#pragma unroll
    for (int j=0;j<8;j++) p[j] = dpp_add<0x118>(p[j]);
    if (s == 0){
#pragma unroll
      for (int j=0;j<8;j++){
        float zv = zb[(long)(i0+j)*2*DI];
        float sz = zv / (1.f + __expf(-zv));
        y16[(i0+j)*16 + dl] = f2bf(fmaf(Dd, xv[j], p[j]) * sz);
      }
    }
  }
  __syncthreads();
  // coalesced store: 16 bf16 per row = 2 x 16B chunks
  for (int lin = tid; lin < TC*2; lin += 256){
    int i = lin >> 1, dd8 = (lin & 1)*8;
    *(bf16x8*)&yg[(r0+i)*DI + d0 + dd8] = *(bf16x8*)&y16[i*16 + dd8];
  }
}

// ---------------- final-row LN (only t = T-1 needed) -> comb half
__global__ __launch_bounds__(64) void k_final(const float* __restrict__ hcur,
    const float* __restrict__ res, const float* __restrict__ nfw, const float* __restrict__ nfb,
    float* __restrict__ comb, int half){
  int b = blockIdx.x;
  int lane = threadIdx.x;
  const float* h = hcur + ((long)b*T + (T-1))*DM;
  const float* r = res  + ((long)b*T + (T-1))*DM;
  float v0 = h[lane]+r[lane], v1 = h[lane+64]+r[lane+64];
  float s = v0+v1;
#pragma unroll
  for (int m=1;m<64;m<<=1) s += __shfl_xor(s, m);
  float mu = s * (1.f/128.f);
  float d0 = v0-mu, d1 = v1-mu;
  float q = d0*d0 + d1*d1;
#pragma unroll
  for (int m=1;m<64;m<<=1) q += __shfl_xor(q, m);
  float rstd = rsqrtf(q*(1.f/128.f) + 1e-5f);
  comb[b*2*DM + half*DM + lane]    = d0*rstd*nfw[lane]    + nfb[lane];
  comb[b*2*DM + half*DM + lane+64] = d1*rstd*nfw[lane+64] + nfb[lane+64];
}

// ---------------- head: out(24,256) = comb(24,256) @ head_w^T + head_b
__global__ __launch_bounds__(256) void k_head(const float* __restrict__ comb,
    const float* __restrict__ hw, const float* __restrict__ hb, float* __restrict__ out){
  int b = blockIdx.x, n = threadIdx.x;
  const float* cr = comb + b*2*DM;
  float acc = hb[n];
#pragma unroll 4
  for (int k=0;k<2*DM;k++) acc = fmaf(cr[k], hw[n*2*DM + k], acc);
  out[b*NC + n] = acc;
}

extern "C" void kernel_launch(void* const* d_in, const int* in_sizes, int n_in,
                              void* d_out, int out_size, void* d_ws, size_t ws_size,
                              hipStream_t stream){
  auto F = [&](int i){ return (const float*)d_in[i]; };
  float* ws = (float*)d_ws;
  size_t o = 0;
  float* h0f = ws + o; o += (size_t)ROWS*DM;
  float* h0b = ws + o; o += (size_t)ROWS*DM;
  float* res = ws + o; o += (size_t)ROWS*DM;
  float* hcur= ws + o; o += (size_t)ROWS*DM;
  float* xz  = ws + o; o += (size_t)ROWS*2*DI;
  float* xc  = ws + o; o += (size_t)ROWS*DI;
  float* gdt = ws + o; o += (size_t)ROWS*DI;
  float* bcg = ws + o; o += (size_t)ROWS*2*DS;
  // bf16 region shared by hn (ROWS*DM), xcb (ROWS*DI), y (ROWS*DI):
  // per-layer lifetimes disjoint: hn -> xz-gemm; xcb: convs -> dbldt; y: scan3 -> out-gemm
  unsigned short* ybf = (unsigned short*)(ws + o); o += (size_t)ROWS*DI/2;
  unsigned short* hnbf = ybf;
  unsigned short* xcb  = ybf;
  float* Pd  = ws + o; o += (size_t)Bb*NCH*DI*DS;
  float* Hl  = ws + o; o += (size_t)Bb*NCH*DI*DS;
  float* Hst = ws + o; o += (size_t)Bb*NCH*DI*DS;
  unsigned short* wbf = (unsigned short*)(ws + o); o += (size_t)2*NL*(2*DI*DM + DM*DI)/2;
  unsigned short* xpb = (unsigned short*)(ws + o); o += (size_t)2*NL*40*DI/2;
  float* comb= ws + o; o += (size_t)Bb*2*DM;

  // weight casts: [f_inp][f_outp][b_inp][b_outp] + xp (both dirs)
  const int NI = NL*2*DI*DM;   // 262144
  const int NO = NL*DM*DI;     // 131072
  const int NX = NL*40*DI;     // 40960
  k_cast<<<(NI+255)/256, 256, 0, stream>>>(F(3),  wbf,            NI);
  k_cast<<<(NO+255)/256, 256, 0, stream>>>(F(11), wbf+NI,         NO);
  k_cast<<<(NI+255)/256, 256, 0, stream>>>(F(14), wbf+NI+NO,      NI);
  k_cast<<<(NO+255)/256, 256, 0, stream>>>(F(22), wbf+2*NI+NO,    NO);
  k_cast<<<(NX+255)/256, 256, 0, stream>>>(F(6),  xpb,            NX);
  k_cast<<<(NX+255)/256, 256, 0, stream>>>(F(17), xpb+NX,         NX);

  k_conv0<<<ROWS*DM/256, 256, 0, stream>>>(F(0), F(1), F(2), h0f, h0b);

  for (int dir = 0; dir < 2; dir++){
    int p = dir ? 14 : 3;   // f_* at 3..13, b_* at 14..24
    const float* hin = dir ? h0b : h0f;
    unsigned short* winp  = wbf + (size_t)dir*(NI+NO);
    unsigned short* woutp = winp + NI;
    for (int l = 0; l < NL; l++){
      const float* hsrc = (l==0) ? hin : hcur;
      k_add_ln<<<ROWS/4, 256, 0, stream>>>(hsrc, res,
          F(p+9)+(size_t)l*DM, F(p+10)+(size_t)l*DM, hnbf, (l==0)?1:0);
      k_mgemm<2*DI, DM><<<dim3(ROWS/128, (2*DI)/128), 256, 0, stream>>>(
          hnbf, winp + (size_t)l*2*DI*DM, xz);
      k_convs<<<ROWS*DI/256, 256, 0, stream>>>(xz,
          F(p+1)+(size_t)l*DI*4, F(p+2)+(size_t)l*DI, xc, xcb);
      k_dbldt<<<ROWS/64, 256, 0, stream>>>(xcb,
          xpb + (size_t)(dir*NL + l)*40*DI,
          F(p+4)+(size_t)l*DI*DTR, F(p+5)+(size_t)l*DI, gdt, bcg);
      k_scan1<<<dim3(DI/16, NCH, Bb), 256, 0, stream>>>(gdt, bcg, xc,
          F(p+6)+(size_t)l*DI*DS, Pd, Hl);
      k_scan2<<<(Bb*DI*DS)/256, 256, 0, stream>>>(Pd, Hl, Hst);
      k_scan3<<<dim3(DI/16, NCH, Bb), 256, 0, stream>>>(gdt, bcg, xc, xz,
          F(p+6)+(size_t)l*DI*DS, F(p+7)+(size_t)l*DI, Hst, ybf);
      k_mgemm64<DM, DI><<<dim3(ROWS/64, DM/128), 256, 0, stream>>>(
          ybf, woutp + (size_t)l*DM*DI, hcur);
    }
    k_final<<<Bb, 64, 0, stream>>>(hcur, res, F(25), F(26), comb, dir);
  }
  k_head<<<Bb, 256, 0, stream>>>(comb, F(27), F(28), (float*)d_out);
}

// Round 12
// 1488.643 us; speedup vs baseline: 1.2737x; 1.2452x over previous
//
#include <hip/hip_runtime.h>
#include <hip/hip_bf16.h>
#include <math.h>

static constexpr int NL=4, DM=128, DI=256, DS=16, DTR=8, NC=256;
static constexpr int Bb=24, Lx=3072, T=1024;
static constexpr int ROWS = Bb*T;       // 24576
static constexpr int NCH=8, TC=128;     // scan chunking

typedef __attribute__((ext_vector_type(4))) float f32x4;
typedef __attribute__((ext_vector_type(8))) short bf16x8;

// f32 -> bf16 (round-to-nearest-even), header-independent
static __device__ inline unsigned short f2bf(float f){
  unsigned int u = __float_as_uint(f);
  unsigned int r = (u + 0x7FFFu + ((u >> 16) & 1u)) >> 16;
  return (unsigned short)r;
}

// DPP-based partial-row add: x += x[lane selected by CTRL]; pure VALU, no DS pipe.
template<int CTRL>
static __device__ __forceinline__ float dpp_add(float x){
  int t = __builtin_amdgcn_update_dpp(0, __float_as_int(x), CTRL, 0xF, 0xF, true);
  return x + __int_as_float(t);
}

// ---------------- initial strided conv: x(B,3072) -> h0 (B,1024,128), plus reversed copy
__global__ __launch_bounds__(256) void k_conv0(const float* __restrict__ x,
    const float* __restrict__ cw, const float* __restrict__ cb,
    float* __restrict__ h0f, float* __restrict__ h0b){
  int idx = blockIdx.x*256 + threadIdx.x;     // B*T*DM total
  int c = idx & (DM-1);
  int t = (idx >> 7) & (T-1);
  int b = idx >> 17;
  const float* xr = x + b*Lx;
  float acc = cb[c];
  int base = 3*t - 1;
#pragma unroll
  for (int k=0;k<3;k++){
    int j = base + k;
    float xv = (j>=0 && j<Lx) ? xr[j] : 0.f;
    acc = fmaf(xv, cw[c*3+k], acc);
  }
  h0f[(b*T + t)*DM + c] = acc;
  h0b[(b*T + (T-1-t))*DM + c] = acc;
}

// ---------------- generic f32 -> bf16 cast
__global__ __launch_bounds__(256) void k_cast(const float* __restrict__ src,
    unsigned short* __restrict__ dst, int n){
  int i = blockIdx.x*256 + threadIdx.x;
  if (i < n) dst[i] = f2bf(src[i]);
}

// ---------------- residual add + LayerNorm over DM=128 -> bf16 hn. 1 wave/row, 4 rows/block
__global__ __launch_bounds__(256) void k_add_ln(const float* __restrict__ hin,
    float* __restrict__ res, const float* __restrict__ lnw, const float* __restrict__ lnb,
    unsigned short* __restrict__ hn, int first){
  int row = blockIdx.x*4 + (threadIdx.x >> 6);
  int lane = threadIdx.x & 63;
  const float* hr = hin + (long)row*DM;
  float* rr = res + (long)row*DM;
  float v0 = hr[lane], v1 = hr[lane+64];
  if (!first){ v0 += rr[lane]; v1 += rr[lane+64]; }
  rr[lane] = v0; rr[lane+64] = v1;
  float s = v0+v1;
#pragma unroll
  for (int m=1;m<64;m<<=1) s += __shfl_xor(s, m);
  float mu = s * (1.f/128.f);
  float d0 = v0-mu, d1 = v1-mu;
  float q = d0*d0 + d1*d1;
#pragma unroll
  for (int m=1;m<64;m<<=1) q += __shfl_xor(q, m);
  float rstd = rsqrtf(q*(1.f/128.f) + 1e-5f);
  hn[(long)row*DM+lane]    = f2bf(d0*rstd*lnw[lane]    + lnb[lane]);
  hn[(long)row*DM+lane+64] = f2bf(d1*rstd*lnw[lane+64] + lnb[lane+64]);
}

// ---------------- bf16 MFMA GEMM: C[M][N](f32) = A[M][K](bf16) * W[N][K](bf16)^T
// tile 128x128, 4 waves (2x2), each wave 64x64 via 4x4 frags of 16x16x32
template<int N, int K>
__global__ __launch_bounds__(256) void k_mgemm(const unsigned short* __restrict__ A,
    const unsigned short* __restrict__ W, float* __restrict__ C){
  constexpr int BK = 32;
  __shared__ short As[128*BK];
  __shared__ short Ws[128*BK];
  int tid = threadIdx.x;
  int lane = tid & 63, wave = tid >> 6;
  int wr = (wave >> 1) * 64, wc = (wave & 1) * 64;
  long bm = blockIdx.x, bn = blockIdx.y;
  const short* Ag = (const short*)A + bm*128*K;
  const short* Wg = (const short*)W + bn*128*K;
  f32x4 acc[4][4] = {};
  int r = lane & 15, kg = (lane >> 4) * 8;
  for (int kb = 0; kb < K; kb += BK){
#pragma unroll
    for (int t = 0; t < 2; t++){
      int c = tid + t*256;            // 512 chunks of 16B per 8KB tile
      int row = c >> 2, kc = (c & 3) * 8;
      *(bf16x8*)&As[row*BK + kc] = *(const bf16x8*)&Ag[row*K + kb + kc];
      *(bf16x8*)&Ws[row*BK + kc] = *(const bf16x8*)&Wg[row*K + kb + kc];
    }
    __syncthreads();
    bf16x8 af[4], wf[4];
#pragma unroll
    for (int m=0;m<4;m++) af[m] = *(const bf16x8*)&As[(wr + m*16 + r)*BK + kg];
#pragma unroll
    for (int n=0;n<4;n++) wf[n] = *(const bf16x8*)&Ws[(wc + n*16 + r)*BK + kg];
#pragma unroll
    for (int m=0;m<4;m++)
#pragma unroll
      for (int n=0;n<4;n++)
        acc[m][n] = __builtin_amdgcn_mfma_f32_16x16x32_bf16(af[m], wf[n], acc[m][n], 0, 0, 0);
    __syncthreads();
  }
  float* Cb = C + (bm*128)*N + bn*128;
  int rq = (lane >> 4) * 4, cn = lane & 15;
#pragma unroll
  for (int m=0;m<4;m++)
#pragma unroll
    for (int n=0;n<4;n++)
#pragma unroll
      for (int q=0;q<4;q++)
        Cb[(wr + m*16 + rq + q)*N + wc + n*16 + cn] = acc[m][n][q];
}

// ---------------- BM=64 variant for the N=128 out-GEMM (2x the blocks -> occupancy)
template<int N, int K>
__global__ __launch_bounds__(256) void k_mgemm64(const unsigned short* __restrict__ A,
    const unsigned short* __restrict__ W, float* __restrict__ C){
  constexpr int BK = 32;
  __shared__ short As[64*BK];    // 4KB
  __shared__ short Ws[128*BK];   // 8KB
  int tid = threadIdx.x;
  int lane = tid & 63, wave = tid >> 6;
  int wr = (wave >> 1) * 32, wc = (wave & 1) * 64;
  long bm = blockIdx.x, bn = blockIdx.y;
  const short* Ag = (const short*)A + bm*64*K;
  const short* Wg = (const short*)W + bn*128*K;
  f32x4 acc[2][4] = {};
  int r = lane & 15, kg = (lane >> 4) * 8;
  for (int kb = 0; kb < K; kb += BK){
    {
      int c = tid;                       // A: 256 chunks of 16B
      int row = c >> 2, kc = (c & 3) * 8;
      *(bf16x8*)&As[row*BK + kc] = *(const bf16x8*)&Ag[row*K + kb + kc];
#pragma unroll
      for (int t = 0; t < 2; t++){       // W: 512 chunks
        int c2 = tid + t*256;
        int row2 = c2 >> 2, kc2 = (c2 & 3) * 8;
        *(bf16x8*)&Ws[row2*BK + kc2] = *(const bf16x8*)&Wg[row2*K + kb + kc2];
      }
    }
    __syncthreads();
    bf16x8 af[2], wf[4];
#pragma unroll
    for (int m=0;m<2;m++) af[m] = *(const bf16x8*)&As[(wr + m*16 + r)*BK + kg];
#pragma unroll
    for (int n=0;n<4;n++) wf[n] = *(const bf16x8*)&Ws[(wc + n*16 + r)*BK + kg];
#pragma unroll
    for (int m=0;m<2;m++)
#pragma unroll
      for (int n=0;n<4;n++)
        acc[m][n] = __builtin_amdgcn_mfma_f32_16x16x32_bf16(af[m], wf[n], acc[m][n], 0, 0, 0);
    __syncthreads();
  }
  float* Cb = C + (bm*64)*N + bn*128;
  int rq = (lane >> 4) * 4, cn = lane & 15;
#pragma unroll
  for (int m=0;m<2;m++)
#pragma unroll
    for (int n=0;n<4;n++)
#pragma unroll
      for (int q=0;q<4;q++)
        Cb[(wr + m*16 + rq + q)*N + wc + n*16 + cn] = acc[m][n][q];
}

// ---------------- causal depthwise conv (k=4, pad 3 left) + SiLU ; x = xz[...,0:256]
// writes f32 xc (for scans) and bf16 xcb (for dbl MFMA)
__global__ __launch_bounds__(256) void k_convs(const float* __restrict__ xz,
    const float* __restrict__ cw, const float* __restrict__ cb,
    float* __restrict__ xc, unsigned short* __restrict__ xcb){
  int idx = blockIdx.x*256 + threadIdx.x;     // B*T*DI
  int d = idx & (DI-1);
  int t = (idx >> 8) & (T-1);
  int b = idx >> 18;
  const float* xrow = xz + (long)b*T*2*DI;
  float acc = cb[d];
#pragma unroll
  for (int k=0;k<4;k++){
    int tt = t + k - 3;
    float xv = (tt>=0) ? xrow[(long)tt*2*DI + d] : 0.f;
    acc = fmaf(xv, cw[d*4+k], acc);
  }
  float s = acc / (1.f + __expf(-acc));
  long o = (long)(b*T+t)*DI + d;
  xc[o] = s;
  xcb[o] = f2bf(s);
}

// ---------------- dbl = xc @ xp^T (40 cols) via MFMA; dt = softplus(dbl[:,:8]@dtw^T+dtb)
__global__ __launch_bounds__(256) void k_dbldt(const unsigned short* __restrict__ xcb,
    const unsigned short* __restrict__ xpb, const float* __restrict__ dtw,
    const float* __restrict__ dtb, float* __restrict__ gdt, float* __restrict__ bcg){
  constexpr int BP = 264;                    // padded row stride (shorts)
  __shared__ short B_s[48*BP];               // 25344 B
  __shared__ float dbl_s[64][9];             // 2304 B
  __shared__ float bc_s[64][33];             // 8448 B
  int tid = threadIdx.x;
  int lane = tid & 63, wave = tid >> 6;
  int wr = wave * 16;                        // wave's row group
  long row0 = (long)blockIdx.x * 64;
  float w[8];
#pragma unroll
  for (int j=0;j<8;j++) w[j] = dtw[tid*8 + j];
  float bias = dtb[tid];
  for (int c = tid; c < 48*32; c += 256){
    int rowp = c >> 5, k8 = (c & 31) * 8;
    bf16x8 v = {};
    if (rowp < 40) v = *(const bf16x8*)&xpb[rowp*256 + k8];
    *(bf16x8*)&B_s[rowp*BP + k8] = v;
  }
  __syncthreads();
  int cf = lane & 15, hi = lane >> 4;
  const short* Ag = (const short*)xcb + (row0 + wr + cf)*DI + hi*8;
  f32x4 acc[3] = {};
#pragma unroll
  for (int ks = 0; ks < 8; ks++){
    bf16x8 af = *(const bf16x8*)&Ag[ks*32];
#pragma unroll
    for (int n = 0; n < 3; n++){
      bf16x8 bf = *(const bf16x8*)&B_s[(n*16 + cf)*BP + ks*32 + hi*8];
      acc[n] = __builtin_amdgcn_mfma_f32_16x16x32_bf16(af, bf, acc[n], 0, 0, 0);
    }
  }
#pragma unroll
  for (int n = 0; n < 3; n++){
    int col = n*16 + cf;
#pragma unroll
    for (int q = 0; q < 4; q++){
      int row = wr + hi*4 + q;
      float v = acc[n][q];
      if (col < 8)       dbl_s[row][col]    = v;
      else if (col < 40) bc_s[row][col - 8] = v;
    }
  }
  __syncthreads();
#pragma unroll
  for (int i = 0; i < 8; i++){
    int idx = tid + i*256;
    int row = idx >> 5, col = idx & 31;
    bcg[(row0 + row)*32 + col] = bc_s[row][col];
  }
  for (int r = 0; r < 64; r++){
    float a = bias;
#pragma unroll
    for (int j = 0; j < 8; j++) a = fmaf(dbl_s[r][j], w[j], a);
    float sp = (a > 20.f) ? a : log1pf(__expf(a));
    gdt[(row0 + r)*DI + tid] = sp;
  }
}

// ---------------- scan pass 1: per-chunk decay product + local final state (h0=0)
// grid (DI/16, NCH, Bb); block 256 = 16 d x 16 s; row-major LDS (R9-proven layout)
__global__ __launch_bounds__(256) void k_scan1(const float* __restrict__ gdt,
    const float* __restrict__ bcg, const float* __restrict__ xc,
    const float* __restrict__ Alog, float* __restrict__ Pd, float* __restrict__ Hl){
  int b = blockIdx.z, ch = blockIdx.y, d0 = blockIdx.x*16;
  int tid = threadIdx.x, s = tid & 15, dl = tid >> 4, d = d0 + dl;
  float A = -__expf(Alog[d*DS + s]);
  __shared__ float dt_s[TC][16], x_s[TC][16], b_s[TC][16];
  long r0 = (long)b*T + ch*TC;
  for (int lin = tid; lin < TC*4; lin += 256){
    int i = lin >> 2, c4 = (lin & 3)*4;
    *(float4*)&dt_s[i][c4] = *(const float4*)&gdt[(r0+i)*DI + d0 + c4];
    *(float4*)&x_s[i][c4]  = *(const float4*)&xc [(r0+i)*DI + d0 + c4];
    *(float4*)&b_s[i][c4]  = *(const float4*)&bcg[(r0+i)*32 + c4];
  }
  __syncthreads();
  float h = 0.f, lp = 0.f;
  for (int i0 = 0; i0 < TC; i0 += 8){
    float dtv[8], xv[8], bv[8];
#pragma unroll
    for (int j=0;j<8;j++){ dtv[j]=dt_s[i0+j][dl]; xv[j]=x_s[i0+j][dl]; bv[j]=b_s[i0+j][s]; }
#pragma unroll
    for (int j=0;j<8;j++){
      float da = dtv[j]*A;
      lp += da;
      h = fmaf(__expf(da), h, dtv[j]*xv[j]*bv[j]);
    }
  }
  long o = ((long)(b*NCH + ch)*DI + d)*DS + s;
  Pd[o] = __expf(lp);
  Hl[o] = h;
}

// ---------------- scan pass 2: sequential chunk combine -> per-chunk start states
__global__ __launch_bounds__(256) void k_scan2(const float* __restrict__ Pd,
    const float* __restrict__ Hl, float* __restrict__ Hst){
  int idx = blockIdx.x*256 + threadIdx.x;   // b*4096 + (d*16+s)
  int b = idx >> 12, j = idx & 4095;
  long base = (long)b*NCH*4096 + j;
  float h = 0.f;
#pragma unroll
  for (int c=0;c<NCH;c++){
    Hst[base + c*4096] = h;
    h = Pd[base + c*4096]*h + Hl[base + c*4096];
  }
}

// ---------------- scan pass 3: full local scan with correct h0, emit gated y (bf16)
// grid (DI/16, NCH, Bb); block 256 = 16 d x 16 s; R9 row-major LDS layout.
// In-loop s==0 epilogue = ONE masked ds_write_b32 of the p-sum; all y math
// (silu(z), D*x+p, bf16 pack) is a vectorized post-loop pass. LDS = 40KB exactly.
__global__ __launch_bounds__(256) void k_scan3(const float* __restrict__ gdt,
    const float* __restrict__ bcg, const float* __restrict__ xc, const float* __restrict__ xz,
    const float* __restrict__ Alog, const float* __restrict__ Dp,
    const float* __restrict__ Hst, unsigned short* __restrict__ yg){
  __shared__ float dt_s[TC][16], x_s[TC][16], b_s[TC][16], c_s[TC][16], y_s[TC][16];
  int b = blockIdx.z, ch = blockIdx.y, d0 = blockIdx.x*16;
  int tid = threadIdx.x, s = tid & 15, dl = tid >> 4, d = d0 + dl;
  float A = -__expf(Alog[d*DS + s]);
  long r0 = (long)b*T + ch*TC;
  for (int lin = tid; lin < TC*4; lin += 256){
    int i = lin >> 2, c4 = (lin & 3)*4;
    *(float4*)&dt_s[i][c4] = *(const float4*)&gdt[(r0+i)*DI + d0 + c4];
    *(float4*)&x_s[i][c4]  = *(const float4*)&xc [(r0+i)*DI + d0 + c4];
    *(float4*)&b_s[i][c4]  = *(const float4*)&bcg[(r0+i)*32 + c4];
    *(float4*)&c_s[i][c4]  = *(const float4*)&bcg[(r0+i)*32 + 16 + c4];
  }
  float h = Hst[((long)(b*NCH + ch)*DI + d)*DS + s];
  __syncthreads();
  for (int i0 = 0; i0 < TC; i0 += 8){
    float dtv[8], xv[8], bv[8], cv[8], dec[8], ad[8], p[8];
#pragma unroll
    for (int j=0;j<8;j++){
      dtv[j]=dt_s[i0+j][dl]; xv[j]=x_s[i0+j][dl];
      bv[j]=b_s[i0+j][s];    cv[j]=c_s[i0+j][s];
    }
#pragma unroll
    for (int j=0;j<8;j++){ dec[j] = __expf(dtv[j]*A); ad[j] = dtv[j]*xv[j]*bv[j]; }
#pragma unroll
    for (int j=0;j<8;j++){ h = fmaf(dec[j], h, ad[j]); p[j] = h * cv[j]; }
    // 4-stage DPP reduce (toward lane 0), 8 independent chains per stage
#pragma unroll
    for (int j=0;j<8;j++) p[j] = dpp_add<0xB1>(p[j]);
#pragma unroll
    for (int j=0;j<8;j++) p[j] = dpp_add<0x4E>(p[j]);
#pragma unroll
    for (int j=0;j<8;j++) p[j] = dpp_add<0x114>(p[j]);
#pragma unroll
    for (int j=0;j<8;j++) p[j] = dpp_add<0x118>(p[j]);
    if (s == 0){
#pragma unroll
      for (int j=0;j<8;j++) y_s[i0+j][dl] = p[j];   // raw p-sum only
    }
  }
  __syncthreads();
  // vectorized y finalize: y = (D*x + p) * silu(z), bf16 pack, coalesced store
  for (int lin = tid; lin < TC*2; lin += 256){
    int i = lin >> 1, o8 = (lin & 1)*8;
    float4 pa = *(float4*)&y_s[i][o8],  pb = *(float4*)&y_s[i][o8+4];
    float4 xa = *(float4*)&x_s[i][o8],  xb = *(float4*)&x_s[i][o8+4];
    const float* zrow = &xz[(r0+i)*2*DI + DI + d0 + o8];
    float4 za = *(const float4*)&zrow[0], zb = *(const float4*)&zrow[4];
    float4 Da = *(const float4*)&Dp[d0+o8], Db = *(const float4*)&Dp[d0+o8+4];
    float pv[8]={pa.x,pa.y,pa.z,pa.w,pb.x,pb.y,pb.z,pb.w};
    float xv[8]={xa.x,xa.y,xa.z,xa.w,xb.x,xb.y,xb.z,xb.w};
    float zv[8]={za.x,za.y,za.z,za.w,zb.x,zb.y,zb.z,zb.w};
    float Dv[8]={Da.x,Da.y,Da.z,Da.w,Db.x,Db.y,Db.z,Db.w};
    bf16x8 v;
#pragma unroll
    for (int k=0;k<8;k++){
      float sz = zv[k] / (1.f + __expf(-zv[k]));
      v[k] = (short)f2bf(fmaf(Dv[k], xv[k], pv[k]) * sz);
    }
    *(bf16x8*)&yg[(r0+i)*DI + d0 + o8] = v;
  }
}

// ---------------- final-row LN (only t = T-1 needed) -> comb half
__global__ __launch_bounds__(64) void k_final(const float* __restrict__ hcur,
    const float* __restrict__ res, const float* __restrict__ nfw, const float* __restrict__ nfb,
    float* __restrict__ comb, int half){
  int b = blockIdx.x;
  int lane = threadIdx.x;
  const float* h = hcur + ((long)b*T + (T-1))*DM;
  const float* r = res  + ((long)b*T + (T-1))*DM;
  float v0 = h[lane]+r[lane], v1 = h[lane+64]+r[lane+64];
  float s = v0+v1;
#pragma unroll
  for (int m=1;m<64;m<<=1) s += __shfl_xor(s, m);
  float mu = s * (1.f/128.f);
  float d0 = v0-mu, d1 = v1-mu;
  float q = d0*d0 + d1*d1;
#pragma unroll
  for (int m=1;m<64;m<<=1) q += __shfl_xor(q, m);
  float rstd = rsqrtf(q*(1.f/128.f) + 1e-5f);
  comb[b*2*DM + half*DM + lane]    = d0*rstd*nfw[lane]    + nfb[lane];
  comb[b*2*DM + half*DM + lane+64] = d1*rstd*nfw[lane+64] + nfb[lane+64];
}

// ---------------- head: out(24,256) = comb(24,256) @ head_w^T + head_b
__global__ __launch_bounds__(256) void k_head(const float* __restrict__ comb,
    const float* __restrict__ hw, const float* __restrict__ hb, float* __restrict__ out){
  int b = blockIdx.x, n = threadIdx.x;
  const float* cr = comb + b*2*DM;
  float acc = hb[n];
#pragma unroll 4
  for (int k=0;k<2*DM;k++) acc = fmaf(cr[k], hw[n*2*DM + k], acc);
  out[b*NC + n] = acc;
}

extern "C" void kernel_launch(void* const* d_in, const int* in_sizes, int n_in,
                              void* d_out, int out_size, void* d_ws, size_t ws_size,
                              hipStream_t stream){
  auto F = [&](int i){ return (const float*)d_in[i]; };
  float* ws = (float*)d_ws;
  size_t o = 0;
  float* h0f = ws + o; o += (size_t)ROWS*DM;
  float* h0b = ws + o; o += (size_t)ROWS*DM;
  float* res = ws + o; o += (size_t)ROWS*DM;
  float* hcur= ws + o; o += (size_t)ROWS*DM;
  float* xz  = ws + o; o += (size_t)ROWS*2*DI;
  float* xc  = ws + o; o += (size_t)ROWS*DI;
  float* gdt = ws + o; o += (size_t)ROWS*DI;
  float* bcg = ws + o; o += (size_t)ROWS*2*DS;
  // bf16 region shared by hn (ROWS*DM), xcb (ROWS*DI), y (ROWS*DI):
  // per-layer lifetimes disjoint: hn -> xz-gemm; xcb: convs -> dbldt; y: scan3 -> out-gemm
  unsigned short* ybf = (unsigned short*)(ws + o); o += (size_t)ROWS*DI/2;
  unsigned short* hnbf = ybf;
  unsigned short* xcb  = ybf;
  float* Pd  = ws + o; o += (size_t)Bb*NCH*DI*DS;
  float* Hl  = ws + o; o += (size_t)Bb*NCH*DI*DS;
  float* Hst = ws + o; o += (size_t)Bb*NCH*DI*DS;
  unsigned short* wbf = (unsigned short*)(ws + o); o += (size_t)2*NL*(2*DI*DM + DM*DI)/2;
  unsigned short* xpb = (unsigned short*)(ws + o); o += (size_t)2*NL*40*DI/2;
  float* comb= ws + o; o += (size_t)Bb*2*DM;

  // weight casts: [f_inp][f_outp][b_inp][b_outp] + xp (both dirs)
  const int NI = NL*2*DI*DM;   // 262144
  const int NO = NL*DM*DI;     // 131072
  const int NX = NL*40*DI;     // 40960
  k_cast<<<(NI+255)/256, 256, 0, stream>>>(F(3),  wbf,            NI);
  k_cast<<<(NO+255)/256, 256, 0, stream>>>(F(11), wbf+NI,         NO);
  k_cast<<<(NI+255)/256, 256, 0, stream>>>(F(14), wbf+NI+NO,      NI);
  k_cast<<<(NO+255)/256, 256, 0, stream>>>(F(22), wbf+2*NI+NO,    NO);
  k_cast<<<(NX+255)/256, 256, 0, stream>>>(F(6),  xpb,            NX);
  k_cast<<<(NX+255)/256, 256, 0, stream>>>(F(17), xpb+NX,         NX);

  k_conv0<<<ROWS*DM/256, 256, 0, stream>>>(F(0), F(1), F(2), h0f, h0b);

  for (int dir = 0; dir < 2; dir++){
    int p = dir ? 14 : 3;   // f_* at 3..13, b_* at 14..24
    const float* hin = dir ? h0b : h0f;
    unsigned short* winp  = wbf + (size_t)dir*(NI+NO);
    unsigned short* woutp = winp + NI;
    for (int l = 0; l < NL; l++){
      const float* hsrc = (l==0) ? hin : hcur;
      k_add_ln<<<ROWS/4, 256, 0, stream>>>(hsrc, res,
          F(p+9)+(size_t)l*DM, F(p+10)+(size_t)l*DM, hnbf, (l==0)?1:0);
      k_mgemm<2*DI, DM><<<dim3(ROWS/128, (2*DI)/128), 256, 0, stream>>>(
          hnbf, winp + (size_t)l*2*DI*DM, xz);
      k_convs<<<ROWS*DI/256, 256, 0, stream>>>(xz,
          F(p+1)+(size_t)l*DI*4, F(p+2)+(size_t)l*DI, xc, xcb);
      k_dbldt<<<ROWS/64, 256, 0, stream>>>(xcb,
          xpb + (size_t)(dir*NL + l)*40*DI,
          F(p+4)+(size_t)l*DI*DTR, F(p+5)+(size_t)l*DI, gdt, bcg);
      k_scan1<<<dim3(DI/16, NCH, Bb), 256, 0, stream>>>(gdt, bcg, xc,
          F(p+6)+(size_t)l*DI*DS, Pd, Hl);
      k_scan2<<<(Bb*DI*DS)/256, 256, 0, stream>>>(Pd, Hl, Hst);
      k_scan3<<<dim3(DI/16, NCH, Bb), 256, 0, stream>>>(gdt, bcg, xc, xz,
          F(p+6)+(size_t)l*DI*DS, F(p+7)+(size_t)l*DI, Hst, ybf);
      k_mgemm64<DM, DI><<<dim3(ROWS/64, DM/128), 256, 0, stream>>>(
          ybf, woutp + (size_t)l*DM*DI, hcur);
    }
    k_final<<<Bb, 64, 0, stream>>>(hcur, res, F(25), F(26), comb, dir);
  }
  k_head<<<Bb, 256, 0, stream>>>(comb, F(27), F(28), (float*)d_out);
}